// Round 1
// baseline (656.720 us; speedup 1.0000x reference)
//
#include <hip/hip_runtime.h>

typedef __attribute__((ext_vector_type(8)))  _Float16 f16x8;
typedef __attribute__((ext_vector_type(2)))  _Float16 f16x2;
typedef __attribute__((ext_vector_type(16))) float    f32x16;

#define BATCH 16384
#define BM 256
#define BN 128
#define BK 32

// ---------------------------------------------------------------------------
// Pre-pass 1: fp32 -> f16 (activations), 8 elems/thread
__global__ void cvt_f16(const float* __restrict__ src, _Float16* __restrict__ dst, int n8) {
    int i = blockIdx.x * blockDim.x + threadIdx.x;
    if (i >= n8) return;
    const float4* s = (const float4*)src + (size_t)i * 2;
    float4 a = s[0], b = s[1];
    f16x8 o;
    o[0] = (_Float16)a.x; o[1] = (_Float16)a.y; o[2] = (_Float16)a.z; o[3] = (_Float16)a.w;
    o[4] = (_Float16)b.x; o[5] = (_Float16)b.y; o[6] = (_Float16)b.z; o[7] = (_Float16)b.w;
    ((f16x8*)dst)[i] = o;
}

// ---------------------------------------------------------------------------
// Pre-pass 2: split weights into f16 hi/lo, packed MFMA-frag-tiled:
// layout [N/32][K/16][hl:2][n&31][ (k>>3)&1 ][k&7]  (f16 elems)
// so one 32x32x16 b-frag (per hl) is a contiguous, lane-coalesced 1 KiB chunk.
__global__ void pack_w(const float* __restrict__ W0, const float* __restrict__ W1,
                       int halfN, _Float16* __restrict__ dst, int K, int lk8) {
    int i = blockIdx.x * blockDim.x + threadIdx.x;
    int K8 = K >> 3;
    int k8 = i & (K8 - 1);
    int n  = i >> lk8;
    const float* src = (W1 != nullptr && n >= halfN) ? (W1 + (size_t)(n - halfN) * K)
                                                     : (W0 + (size_t)n * K);
    const float4* s = (const float4*)(src + (size_t)k8 * 8);
    float4 a = s[0], b = s[1];
    float v[8] = {a.x, a.y, a.z, a.w, b.x, b.y, b.z, b.w};
    f16x8 h, l;
#pragma unroll
    for (int j = 0; j < 8; ++j) {
        _Float16 hh = (_Float16)v[j];
        h[j] = hh;
        l[j] = (_Float16)(v[j] - (float)hh);
    }
    int nb = n >> 5, r = n & 31, kb = k8 >> 1, ks = k8 & 1;
    size_t base = (((size_t)nb * (K >> 4) + kb) * 2) * 512 + (size_t)(r * 2 + ks) * 8;
    *(f16x8*)(dst + base)       = h;   // hi plane
    *(f16x8*)(dst + base + 512) = l;   // lo plane
}

// ---------------------------------------------------------------------------
// GEMM: C[M,N] (f16) = A[M,K](f16) * B^T + bias, B pre-split/packed (hi+lo).
// Block 256 thr = 4 waves (2x2), wave tile 128x64 of 32x32x16 MFMAs, 2-term.
template<int K, int N>
__global__ __launch_bounds__(256, 2)
void gemm_split(const _Float16* __restrict__ A, const _Float16* __restrict__ Bp,
                const float* __restrict__ bias0, const float* __restrict__ bias1,
                int nb0, _Float16* __restrict__ C) {
    __shared__ _Float16 Alds[BM * BK];     // 16 KiB, slot-swizzled
    const int t    = threadIdx.x;
    const int wid  = t >> 6, lane = t & 63;
    const int wr   = wid >> 1, wc = wid & 1;
    const int l31  = lane & 31, l5 = lane >> 5;

    constexpr int nwg = (BATCH / BM) * (N / BN);
    int bx  = blockIdx.x;
    int swz = (bx & 7) * (nwg >> 3) + (bx >> 3);   // XCD-chunked (nwg%8==0)
    int mT  = swz & 63;                            // 64 M-tiles
    int nT  = swz >> 6;
    const size_t m0 = (size_t)mT * BM;
    const int    n0 = nT * BN;

    f32x16 acc[4][2];
#pragma unroll
    for (int mi = 0; mi < 4; ++mi)
#pragma unroll
        for (int ni = 0; ni < 2; ++ni)
#pragma unroll
            for (int r = 0; r < 16; ++r) acc[mi][ni][r] = 0.f;

    const int srow  = t >> 2;   // + i*64 per staging instr
    const int sslot = t & 3;

    // b-frag base: NB = nT*4 + wc*2 (+ni);  lane offset (l31*2+l5)*8 elems
    const _Float16* Bbase = Bp + ((size_t)(nT * 4 + wc * 2) * (K / 16) * 2) * 512
                               + (size_t)(l31 * 2 + l5) * 8;

    const int KT = K / BK;
    for (int kt = 0; kt < KT; ++kt) {
        __syncthreads();
        // --- stage A tile (256x32 f16 = 16 KiB) via global_load_lds, swizzled src
#pragma unroll
        for (int i = 0; i < 4; ++i) {
            int row = i * 64 + srow;
            const _Float16* src = A + (m0 + row) * K + kt * BK + ((sslot ^ (row & 3)) * 8);
            __builtin_amdgcn_global_load_lds(
                (const __attribute__((address_space(1))) void*)src,
                (__attribute__((address_space(3))) void*)(Alds + i * 2048 + wid * 512),
                16, 0, 0);
        }
        // --- b-frags direct from global (packed, coalesced 1 KiB per frag)
        f16x8 bh[2][2], bl[2][2];   // [ksub][ni]
#pragma unroll
        for (int ni = 0; ni < 2; ++ni)
#pragma unroll
            for (int ks = 0; ks < 2; ++ks) {
                const _Float16* fb = Bbase + (size_t)ni * ((K / 16) * 1024)
                                           + ((size_t)(kt * 2 + ks) * 2) * 512;
                bh[ks][ni] = *(const f16x8*)(fb);
                bl[ks][ni] = *(const f16x8*)(fb + 512);
            }
        __syncthreads();
        // --- a-frags from LDS (swizzled read)
        f16x8 af[4][2];   // [mi][ksub]
#pragma unroll
        for (int mi = 0; mi < 4; ++mi)
#pragma unroll
            for (int ks = 0; ks < 2; ++ks) {
                int row  = wr * 128 + mi * 32 + l31;
                int slot = ks * 2 + l5;
                int boff = row * 64 + ((slot ^ (row & 3)) << 4);
                af[mi][ks] = *(const f16x8*)((const char*)Alds + boff);
            }
        // --- MFMA: acc += A*Bh ; acc += A*Bl
#pragma unroll
        for (int ks = 0; ks < 2; ++ks)
#pragma unroll
            for (int mi = 0; mi < 4; ++mi)
#pragma unroll
                for (int ni = 0; ni < 2; ++ni) {
                    acc[mi][ni] = __builtin_amdgcn_mfma_f32_32x32x16_f16(
                        af[mi][ks], bh[ks][ni], acc[mi][ni], 0, 0, 0);
                    acc[mi][ni] = __builtin_amdgcn_mfma_f32_32x32x16_f16(
                        af[mi][ks], bl[ks][ni], acc[mi][ni], 0, 0, 0);
                }
    }
    // --- epilogue: +bias, f16 store.  C/D map: col=lane&31, row=(r&3)+8*(r>>2)+4*(lane>>5)
#pragma unroll
    for (int mi = 0; mi < 4; ++mi)
#pragma unroll
        for (int ni = 0; ni < 2; ++ni) {
            int n = n0 + wc * 64 + ni * 32 + l31;
            float bias = (n < nb0) ? bias0[n] : bias1[n - nb0];
#pragma unroll
            for (int r = 0; r < 16; ++r) {
                size_t row = m0 + wr * 128 + mi * 32 + (r & 3) + 8 * (r >> 2) + 4 * l5;
                C[row * N + n] = (_Float16)(acc[mi][ni][r] + bias);
            }
        }
}

// ---------------------------------------------------------------------------
// Fused attention (8 heads x 128, per-row 8x8 scores) + residual + LayerNorm.
// One wave per batch row; Q/K rows staged in padded LDS, V/text in registers.
__global__ __launch_bounds__(256)
void attn_ln(const _Float16* __restrict__ Qb, const _Float16* __restrict__ KVb,
             const float* __restrict__ text, const float* __restrict__ gamma,
             const float* __restrict__ beta, float* __restrict__ out) {
    __shared__ __align__(16) _Float16 qlds[4][8][136];
    __shared__ __align__(16) _Float16 klds[4][8][136];
    const int t = threadIdx.x, wid = t >> 6, lane = t & 63;
    const size_t b = (size_t)blockIdx.x * 4 + wid;
    const _Float16* qrow  = Qb  + b * 1024;
    const _Float16* kvrow = KVb + b * 2048;

#pragma unroll
    for (int i = 0; i < 2; ++i) {
        int e8 = i * 64 + lane;            // 0..127 (8-elem groups)
        int h = e8 >> 4, dd = (e8 & 15) * 8;
        *(f16x8*)&qlds[wid][h][dd] = *(const f16x8*)(qrow + (size_t)e8 * 8);
        *(f16x8*)&klds[wid][h][dd] = *(const f16x8*)(kvrow + (size_t)e8 * 8);
    }
    f16x2 V[8]; float2 X[8];
#pragma unroll
    for (int j = 0; j < 8; ++j) {
        V[j] = *(const f16x2*)(kvrow + 1024 + j * 128 + lane * 2);
        X[j] = *(const float2*)(text + b * 1024 + j * 128 + lane * 2);
    }
    __syncthreads();

    // scores: lane (h,g) computes Q[h].K[g] over 128 dims
    const int h = lane >> 3, g = lane & 7;
    float s0 = 0.f, s1 = 0.f;
#pragma unroll
    for (int d8 = 0; d8 < 16; ++d8) {
        f16x8 qv = *(const f16x8*)&qlds[wid][h][d8 * 8];
        f16x8 kv = *(const f16x8*)&klds[wid][g][d8 * 8];
#pragma unroll
        for (int j = 0; j < 4; ++j) s0 += (float)qv[j] * (float)kv[j];
#pragma unroll
        for (int j = 4; j < 8; ++j) s1 += (float)qv[j] * (float)kv[j];
    }
    float s = (s0 + s1) * 0.08838834764831843f;   // 1/sqrt(128)

    // softmax over g (8-lane groups)
    float mx = s;
    mx = fmaxf(mx, __shfl_xor(mx, 1));
    mx = fmaxf(mx, __shfl_xor(mx, 2));
    mx = fmaxf(mx, __shfl_xor(mx, 4));
    float p = __expf(s - mx);
    float sm = p;
    sm += __shfl_xor(sm, 1); sm += __shfl_xor(sm, 2); sm += __shfl_xor(sm, 4);
    float attn = p / sm;

    // PV: out elem e = 128*j + 2*lane + c  -> head j, lane-local V regs
    float2 o[8];
#pragma unroll
    for (int j = 0; j < 8; ++j) { o[j].x = 0.f; o[j].y = 0.f; }
#pragma unroll
    for (int j = 0; j < 8; ++j)
#pragma unroll
        for (int gg = 0; gg < 8; ++gg) {
            float a = __shfl(attn, j * 8 + gg);
            o[j].x += a * (float)V[gg][0];
            o[j].y += a * (float)V[gg][1];
        }

    // residual + LayerNorm
    float sum = 0.f, ssq = 0.f;
    float2 xr[8];
#pragma unroll
    for (int j = 0; j < 8; ++j) {
        float2 x; x.x = X[j].x + o[j].x; x.y = X[j].y + o[j].y;
        xr[j] = x;
        sum += x.x + x.y;
        ssq += x.x * x.x + x.y * x.y;
    }
#pragma unroll
    for (int off = 1; off < 64; off <<= 1) {
        sum += __shfl_xor(sum, off);
        ssq += __shfl_xor(ssq, off);
    }
    float mu  = sum * (1.f / 1024.f);
    float var = ssq * (1.f / 1024.f) - mu * mu;
    float rs  = 1.f / sqrtf(var + 1e-5f);
    float* orow = out + b * 1024;
#pragma unroll
    for (int j = 0; j < 8; ++j) {
        float2 gm = *(const float2*)(gamma + j * 128 + lane * 2);
        float2 bt = *(const float2*)(beta  + j * 128 + lane * 2);
        float2 y;
        y.x = (xr[j].x - mu) * rs * gm.x + bt.x;
        y.y = (xr[j].y - mu) * rs * gm.y + bt.y;
        *(float2*)(orow + j * 128 + lane * 2) = y;
    }
}

// ---------------------------------------------------------------------------
extern "C" void kernel_launch(void* const* d_in, const int* in_sizes, int n_in,
                              void* d_out, int out_size, void* d_ws, size_t ws_size,
                              hipStream_t stream) {
    const float* text  = (const float*)d_in[0];
    const float* image = (const float*)d_in[1];
    const float* Wq    = (const float*)d_in[2];
    const float* bq    = (const float*)d_in[3];
    const float* Wk    = (const float*)d_in[4];
    const float* bk    = (const float*)d_in[5];
    const float* Wv    = (const float*)d_in[6];
    const float* bv    = (const float*)d_in[7];
    const float* gamma = (const float*)d_in[8];
    const float* beta  = (const float*)d_in[9];
    float* out = (float*)d_out;

    char* ws = (char*)d_ws;
    _Float16* textH = (_Float16*)ws; ws += (size_t)BATCH * 1024 * 2;
    _Float16* imgH  = (_Float16*)ws; ws += (size_t)BATCH * 2048 * 2;
    _Float16* WqP   = (_Float16*)ws; ws += (size_t)1024 * 1024 * 2 * 2;
    _Float16* WkvP  = (_Float16*)ws; ws += (size_t)2048 * 2048 * 2 * 2;
    _Float16* Qb    = (_Float16*)ws; ws += (size_t)BATCH * 1024 * 2;
    _Float16* KVb   = (_Float16*)ws; ws += (size_t)BATCH * 2048 * 2;

    cvt_f16<<<(BATCH * 1024 / 8) / 256, 256, 0, stream>>>(text,  textH, BATCH * 1024 / 8);
    cvt_f16<<<(BATCH * 2048 / 8) / 256, 256, 0, stream>>>(image, imgH,  BATCH * 2048 / 8);
    pack_w<<<(1024 * 128) / 256, 256, 0, stream>>>(Wq, nullptr, 1024, WqP, 1024, 7);
    pack_w<<<(2048 * 256) / 256, 256, 0, stream>>>(Wk, Wv, 1024, WkvP, 2048, 8);
    gemm_split<1024, 1024><<<512,  256, 0, stream>>>(textH, WqP,  bq, bq, 1024, Qb);
    gemm_split<2048, 2048><<<1024, 256, 0, stream>>>(imgH,  WkvP, bk, bv, 1024, KVb);
    attn_ln<<<BATCH / 4, 256, 0, stream>>>(Qb, KVb, text, gamma, beta, out);
}